// Round 1
// baseline (207.813 us; speedup 1.0000x reference)
//
#include <hip/hip_runtime.h>
#include <hip/hip_bf16.h>

using bf16 = __hip_bfloat16;
typedef __attribute__((ext_vector_type(8))) short frag_ab;   // 8 bf16
typedef __attribute__((ext_vector_type(4))) float frag_cd;   // 4 fp32

constexpr float TEMP   = 0.07f;
constexpr float INVT   = 1.0f / TEMP;                 // = M (fixed logsumexp shift)
constexpr float THRESH = 0.1f;
constexpr float EPS    = 1e-8f;
constexpr float LOG2E  = 1.4426950408889634f;
constexpr float C1     = LOG2E / TEMP;                // exp((s-1)/T) = exp2(s*C1 - C1)

constexpr int D      = 128;
constexpr int SPLITS = 4;     // column splits (grid.y)
constexpr int TI     = 64;    // rows per block
constexpr int TJ     = 64;    // cols per LDS tile
constexpr int CPS    = 2048;  // cols per split (8192/4)

// ---------------- kernel 1: row-normalize, cast to bf16 ----------------
__global__ __launch_bounds__(256) void k1_normalize(
    const float* __restrict__ f, bf16* __restrict__ fn, int n)
{
    const int row  = blockIdx.x * 4 + (threadIdx.x >> 6);
    const int lane = threadIdx.x & 63;
    float2 v = ((const float2*)(f + (size_t)row * D))[lane];
    float ss = v.x * v.x + v.y * v.y;
    #pragma unroll
    for (int m = 32; m >= 1; m >>= 1) ss += __shfl_xor(ss, m, 64);
    const float inv = 1.0f / fmaxf(sqrtf(ss), EPS);
    __hip_bfloat162 o;
    o.x = __float2bfloat16(v.x * inv);
    o.y = __float2bfloat16(v.y * inv);
    ((__hip_bfloat162*)(fn + (size_t)row * D))[lane] = o;
}

// ---------------- kernel 2: fused sim + masked reductions ----------------
// grid = (n/TI, SPLITS), block = 256 (4 waves; wave w owns rows [TI*bx + 16w, +16))
__global__ __launch_bounds__(256) void k2_main(
    const bf16* __restrict__ fn, const float* __restrict__ lab,
    float* __restrict__ se_p, float* __restrict__ sp_p,
    float* __restrict__ cnt_p, int n)
{
    __shared__ float lab_s[CPS];
    __shared__ bf16  colbuf[TJ][D + 8];   // +8 bf16 pad -> 2-way max bank aliasing

    const int tid  = threadIdx.x;
    const int wave = tid >> 6;
    const int lane = tid & 63;
    const int quad = lane >> 4;
    const int l15  = lane & 15;

    const int rb     = blockIdx.x;
    const int split  = blockIdx.y;
    const int cps    = n / SPLITS;
    const int cbase0 = split * cps;

    for (int i = tid; i < cps; i += 256) lab_s[i] = lab[cbase0 + i];

    const int row_base = rb * TI + wave * 16;

    // A fragments for this wave's 16 rows: row m = row_base + l15, k = kb*32 + quad*8 + j
    frag_ab afr[4];
    {
        const bf16* ap = fn + (size_t)(row_base + l15) * D + quad * 8;
        afr[0] = *(const frag_ab*)(ap);
        afr[1] = *(const frag_ab*)(ap + 32);
        afr[2] = *(const frag_ab*)(ap + 64);
        afr[3] = *(const frag_ab*)(ap + 96);
    }
    float li[4];
    #pragma unroll
    for (int r = 0; r < 4; ++r) li[r] = lab[row_base + quad * 4 + r];

    float se[4]  = {0.f, 0.f, 0.f, 0.f};
    float sp[4]  = {0.f, 0.f, 0.f, 0.f};
    float cnt[4] = {0.f, 0.f, 0.f, 0.f};

    const int ntiles = cps / TJ;
    for (int jt = 0; jt < ntiles; ++jt) {
        __syncthreads();   // protect colbuf from previous iteration's readers
        {   // stage TJ cols x 128 bf16, fully coalesced 16B/lane
            const int chunk = tid & 15;
            const int c0    = tid >> 4;   // 0..15
            const bf16* gp = fn + (size_t)(cbase0 + jt * TJ + c0) * D + chunk * 8;
            #pragma unroll
            for (int cc = 0; cc < 4; ++cc) {
                frag_ab v = *(const frag_ab*)(gp + (size_t)cc * 16 * D);
                *(frag_ab*)(&colbuf[cc * 16 + c0][chunk * 8]) = v;
            }
        }
        __syncthreads();

        #pragma unroll
        for (int sub = 0; sub < 4; ++sub) {
            const int c = sub * 16 + l15;          // output col within tile
            const bf16* bp = &colbuf[c][quad * 8];
            frag_ab b0 = *(const frag_ab*)(bp);
            frag_ab b1 = *(const frag_ab*)(bp + 32);
            frag_ab b2 = *(const frag_ab*)(bp + 64);
            frag_ab b3 = *(const frag_ab*)(bp + 96);
            frag_cd acc = {0.f, 0.f, 0.f, 0.f};
            acc = __builtin_amdgcn_mfma_f32_16x16x32_bf16(afr[0], b0, acc, 0, 0, 0);
            acc = __builtin_amdgcn_mfma_f32_16x16x32_bf16(afr[1], b1, acc, 0, 0, 0);
            acc = __builtin_amdgcn_mfma_f32_16x16x32_bf16(afr[2], b2, acc, 0, 0, 0);
            acc = __builtin_amdgcn_mfma_f32_16x16x32_bf16(afr[3], b3, acc, 0, 0, 0);

            const float lj = lab_s[jt * TJ + c];
            #pragma unroll
            for (int r = 0; r < 4; ++r) {
                const float s = acc[r];                       // raw dot (cosine)
                const float e = __builtin_amdgcn_exp2f(__builtin_fmaf(s, C1, -C1));
                const bool pos = fabsf(li[r] - lj) < THRESH;  // includes diagonal; fixed in k3
                se[r]  += e;
                sp[r]  += pos ? s : 0.0f;                     // raw dots; scale by 1/T in k3
                cnt[r] += pos ? 1.0f : 0.0f;
            }
        }
    }

    // reduce across the 16 lanes of each quad-group (same rows, cols mod 16)
    #pragma unroll
    for (int r = 0; r < 4; ++r) {
        #pragma unroll
        for (int m = 1; m < 16; m <<= 1) {
            se[r]  += __shfl_xor(se[r],  m, 64);
            sp[r]  += __shfl_xor(sp[r],  m, 64);
            cnt[r] += __shfl_xor(cnt[r], m, 64);
        }
    }
    if (l15 == 0) {
        #pragma unroll
        for (int r = 0; r < 4; ++r) {
            const int i = row_base + quad * 4 + r;
            se_p[(size_t)split * n + i]  = se[r];
            sp_p[(size_t)split * n + i]  = sp[r];
            cnt_p[(size_t)split * n + i] = cnt[r];
        }
    }
}

// ---------------- kernel 3: diagonal correction + finalize ----------------
__global__ __launch_bounds__(256) void k3_finalize(
    const bf16* __restrict__ fn, const float* __restrict__ se_p,
    const float* __restrict__ sp_p, const float* __restrict__ cnt_p,
    float* __restrict__ out, int n)
{
    const int row  = blockIdx.x * 4 + (threadIdx.x >> 6);
    const int lane = threadIdx.x & 63;
    __hip_bfloat162 v = ((const __hip_bfloat162*)(fn + (size_t)row * D))[lane];
    const float a = __bfloat162float(v.x), b = __bfloat162float(v.y);
    float ss = a * a + b * b;
    #pragma unroll
    for (int m = 32; m >= 1; m >>= 1) ss += __shfl_xor(ss, m, 64);
    if (lane == 0) {
        float se = 0.f, sp = 0.f, cnt = 0.f;
        for (int s = 0; s < SPLITS; ++s) {
            se  += se_p[(size_t)s * n + row];
            sp  += sp_p[(size_t)s * n + row];
            cnt += cnt_p[(size_t)s * n + row];
        }
        const float s_ii = ss;  // diagonal raw dot of the bf16 row (matches MFMA to ~1e-6)
        se  -= __builtin_amdgcn_exp2f(__builtin_fmaf(s_ii, C1, -C1));
        sp  -= s_ii;
        cnt -= 1.0f;
        const float log_denom = INVT + __logf(se);
        const float loss = log_denom - (sp * INVT) / fmaxf(cnt, 1.0f);
        atomicAdd(out, loss / (float)n);
    }
}

extern "C" void kernel_launch(void* const* d_in, const int* in_sizes, int n_in,
                              void* d_out, int out_size, void* d_ws, size_t ws_size,
                              hipStream_t stream) {
    const float* feat = (const float*)d_in[0];
    const float* lab  = (const float*)d_in[1];
    const int n = in_sizes[1];              // 8192
    float* out = (float*)d_out;

    // ws layout: fn (n*D bf16) | se_p | sp_p | cnt_p  (each SPLITS*n fp32) ≈ 2.4 MB
    char* ws = (char*)d_ws;
    bf16* fn = (bf16*)ws;
    size_t off = (size_t)n * D * sizeof(bf16);
    float* se_p  = (float*)(ws + off); off += (size_t)SPLITS * n * sizeof(float);
    float* sp_p  = (float*)(ws + off); off += (size_t)SPLITS * n * sizeof(float);
    float* cnt_p = (float*)(ws + off);

    hipMemsetAsync(out, 0, sizeof(float), stream);
    k1_normalize<<<n / 4, 256, 0, stream>>>(feat, fn, n);
    dim3 g2(n / TI, SPLITS);
    k2_main<<<g2, 256, 0, stream>>>(fn, lab, se_p, sp_p, cnt_p, n);
    k3_finalize<<<n / 4, 256, 0, stream>>>(fn, se_p, sp_p, cnt_p, out, n);
}

// Round 2
// 106.386 us; speedup vs baseline: 1.9534x; 1.9534x over previous
//
#include <hip/hip_runtime.h>
#include <hip/hip_bf16.h>

using bf16 = __hip_bfloat16;
typedef __attribute__((ext_vector_type(8))) short frag_ab;   // 8 bf16
typedef __attribute__((ext_vector_type(4))) float frag_cd;   // 4 fp32

constexpr float TEMP   = 0.07f;
constexpr float INVT   = 1.0f / TEMP;                 // = M (fixed logsumexp shift)
constexpr float THRESH = 0.1f;
constexpr float EPS    = 1e-8f;
constexpr float LOG2E  = 1.4426950408889634f;
constexpr float C1     = LOG2E / TEMP;                // exp((s-1)/T) = exp2(s*C1 - C1)

constexpr int D      = 128;
constexpr int SPLITS = 8;     // column splits (grid.y) -> 1024 blocks, 4/CU
constexpr int TI     = 64;    // rows per block
constexpr int TJ     = 64;    // cols per LDS tile

// ---------------- kernel 1: row-normalize, cast to bf16 ----------------
__global__ __launch_bounds__(256) void k1_normalize(
    const float* __restrict__ f, bf16* __restrict__ fn, int n)
{
    const int row  = blockIdx.x * 4 + (threadIdx.x >> 6);
    const int lane = threadIdx.x & 63;
    float2 v = ((const float2*)(f + (size_t)row * D))[lane];
    float ss = v.x * v.x + v.y * v.y;
    #pragma unroll
    for (int m = 32; m >= 1; m >>= 1) ss += __shfl_xor(ss, m, 64);
    const float inv = 1.0f / fmaxf(sqrtf(ss), EPS);
    __hip_bfloat162 o;
    o.x = __float2bfloat16(v.x * inv);
    o.y = __float2bfloat16(v.y * inv);
    ((__hip_bfloat162*)(fn + (size_t)row * D))[lane] = o;
}

// ---------------- kernel 2: fused sim + masked reductions ----------------
// grid = (n/TI, SPLITS), block = 256 (4 waves; wave w owns rows [TI*bx + 16w, +16))
__global__ __launch_bounds__(256) void k2_main(
    const bf16* __restrict__ fn, const float* __restrict__ lab,
    float* __restrict__ se_p, float* __restrict__ sp_p,
    float* __restrict__ cnt_p, int n)
{
    __shared__ float lab_s[1024];         // cps = 8192/8 = 1024
    __shared__ bf16  colbuf[TJ][D + 8];   // +8 bf16 pad -> 2-way max bank aliasing

    const int tid  = threadIdx.x;
    const int wave = tid >> 6;
    const int lane = tid & 63;
    const int quad = lane >> 4;
    const int l15  = lane & 15;

    const int rb     = blockIdx.x;
    const int split  = blockIdx.y;
    const int cps    = n / SPLITS;
    const int cbase0 = split * cps;

    for (int i = tid; i < cps; i += 256) lab_s[i] = lab[cbase0 + i];

    const int row_base = rb * TI + wave * 16;

    // A fragments for this wave's 16 rows: row m = row_base + l15, k = kb*32 + quad*8 + j
    frag_ab afr[4];
    {
        const bf16* ap = fn + (size_t)(row_base + l15) * D + quad * 8;
        afr[0] = *(const frag_ab*)(ap);
        afr[1] = *(const frag_ab*)(ap + 32);
        afr[2] = *(const frag_ab*)(ap + 64);
        afr[3] = *(const frag_ab*)(ap + 96);
    }
    float li[4];
    #pragma unroll
    for (int r = 0; r < 4; ++r) li[r] = lab[row_base + quad * 4 + r];

    float se[4]  = {0.f, 0.f, 0.f, 0.f};
    float sp[4]  = {0.f, 0.f, 0.f, 0.f};
    float cnt[4] = {0.f, 0.f, 0.f, 0.f};

    const int ntiles = cps / TJ;
    for (int jt = 0; jt < ntiles; ++jt) {
        __syncthreads();   // protect colbuf from previous iteration's readers
        {   // stage TJ cols x 128 bf16, fully coalesced 16B/lane
            const int chunk = tid & 15;
            const int c0    = tid >> 4;   // 0..15
            const bf16* gp = fn + (size_t)(cbase0 + jt * TJ + c0) * D + chunk * 8;
            #pragma unroll
            for (int cc = 0; cc < 4; ++cc) {
                frag_ab v = *(const frag_ab*)(gp + (size_t)cc * 16 * D);
                *(frag_ab*)(&colbuf[cc * 16 + c0][chunk * 8]) = v;
            }
        }
        __syncthreads();

        #pragma unroll
        for (int sub = 0; sub < 4; ++sub) {
            const int c = sub * 16 + l15;          // output col within tile
            const bf16* bp = &colbuf[c][quad * 8];
            frag_ab b0 = *(const frag_ab*)(bp);
            frag_ab b1 = *(const frag_ab*)(bp + 32);
            frag_ab b2 = *(const frag_ab*)(bp + 64);
            frag_ab b3 = *(const frag_ab*)(bp + 96);
            frag_cd acc = {0.f, 0.f, 0.f, 0.f};
            acc = __builtin_amdgcn_mfma_f32_16x16x32_bf16(afr[0], b0, acc, 0, 0, 0);
            acc = __builtin_amdgcn_mfma_f32_16x16x32_bf16(afr[1], b1, acc, 0, 0, 0);
            acc = __builtin_amdgcn_mfma_f32_16x16x32_bf16(afr[2], b2, acc, 0, 0, 0);
            acc = __builtin_amdgcn_mfma_f32_16x16x32_bf16(afr[3], b3, acc, 0, 0, 0);

            const float lj = lab_s[jt * TJ + c];
            #pragma unroll
            for (int r = 0; r < 4; ++r) {
                const float s = acc[r];                       // raw dot (cosine)
                const float e = __builtin_amdgcn_exp2f(__builtin_fmaf(s, C1, -C1));
                const bool pos = fabsf(li[r] - lj) < THRESH;  // includes diagonal; fixed in k3
                se[r]  += e;
                sp[r]  += pos ? s : 0.0f;                     // raw dots; scale by 1/T in k3
                cnt[r] += pos ? 1.0f : 0.0f;
            }
        }
    }

    // reduce across the 16 lanes of each quad-group (same rows, cols mod 16)
    #pragma unroll
    for (int r = 0; r < 4; ++r) {
        #pragma unroll
        for (int m = 1; m < 16; m <<= 1) {
            se[r]  += __shfl_xor(se[r],  m, 64);
            sp[r]  += __shfl_xor(sp[r],  m, 64);
            cnt[r] += __shfl_xor(cnt[r], m, 64);
        }
    }
    if (l15 == 0) {
        #pragma unroll
        for (int r = 0; r < 4; ++r) {
            const int i = row_base + quad * 4 + r;
            se_p[(size_t)split * n + i]  = se[r];
            sp_p[(size_t)split * n + i]  = sp[r];
            cnt_p[(size_t)split * n + i] = cnt[r];
        }
    }
}

// ---------------- kernel 3: diagonal correction + per-row loss ----------------
__global__ __launch_bounds__(256) void k3_finalize(
    const bf16* __restrict__ fn, const float* __restrict__ se_p,
    const float* __restrict__ sp_p, const float* __restrict__ cnt_p,
    float* __restrict__ loss_row, int n)
{
    const int row  = blockIdx.x * 4 + (threadIdx.x >> 6);
    const int lane = threadIdx.x & 63;
    __hip_bfloat162 v = ((const __hip_bfloat162*)(fn + (size_t)row * D))[lane];
    const float a = __bfloat162float(v.x), b = __bfloat162float(v.y);
    float ss = a * a + b * b;
    #pragma unroll
    for (int m = 32; m >= 1; m >>= 1) ss += __shfl_xor(ss, m, 64);
    if (lane == 0) {
        float se = 0.f, sp = 0.f, cnt = 0.f;
        #pragma unroll
        for (int s = 0; s < SPLITS; ++s) {
            se  += se_p[(size_t)s * n + row];
            sp  += sp_p[(size_t)s * n + row];
            cnt += cnt_p[(size_t)s * n + row];
        }
        const float s_ii = ss;  // diagonal raw dot of the bf16 row (matches MFMA to ~1e-6)
        se  -= __builtin_amdgcn_exp2f(__builtin_fmaf(s_ii, C1, -C1));
        sp  -= s_ii;
        cnt -= 1.0f;
        const float log_denom = INVT + __logf(se);
        loss_row[row] = log_denom - (sp * INVT) / fmaxf(cnt, 1.0f);
    }
}

// ---------------- kernel 4: single-block mean reduction ----------------
__global__ __launch_bounds__(256) void k4_reduce(
    const float* __restrict__ loss_row, float* __restrict__ out, int n)
{
    float s = 0.f;
    for (int i = threadIdx.x; i < n; i += 256) s += loss_row[i];
    #pragma unroll
    for (int m = 32; m >= 1; m >>= 1) s += __shfl_xor(s, m, 64);
    __shared__ float wsum[4];
    if ((threadIdx.x & 63) == 0) wsum[threadIdx.x >> 6] = s;
    __syncthreads();
    if (threadIdx.x == 0)
        out[0] = (wsum[0] + wsum[1] + wsum[2] + wsum[3]) / (float)n;
}

extern "C" void kernel_launch(void* const* d_in, const int* in_sizes, int n_in,
                              void* d_out, int out_size, void* d_ws, size_t ws_size,
                              hipStream_t stream) {
    const float* feat = (const float*)d_in[0];
    const float* lab  = (const float*)d_in[1];
    const int n = in_sizes[1];              // 8192
    float* out = (float*)d_out;

    // ws layout: fn (n*D bf16 = 2 MB) | se_p | sp_p | cnt_p (each SPLITS*n fp32) | loss_row
    char* ws = (char*)d_ws;
    bf16* fn = (bf16*)ws;
    size_t off = (size_t)n * D * sizeof(bf16);
    float* se_p  = (float*)(ws + off); off += (size_t)SPLITS * n * sizeof(float);
    float* sp_p  = (float*)(ws + off); off += (size_t)SPLITS * n * sizeof(float);
    float* cnt_p = (float*)(ws + off); off += (size_t)SPLITS * n * sizeof(float);
    float* loss_row = (float*)(ws + off);

    k1_normalize<<<n / 4, 256, 0, stream>>>(feat, fn, n);
    dim3 g2(n / TI, SPLITS);
    k2_main<<<g2, 256, 0, stream>>>(fn, lab, se_p, sp_p, cnt_p, n);
    k3_finalize<<<n / 4, 256, 0, stream>>>(fn, se_p, sp_p, cnt_p, loss_row, n);
    k4_reduce<<<1, 256, 0, stream>>>(loss_row, out, n);
}